// Round 8
// baseline (107.800 us; speedup 1.0000x reference)
//
#include <hip/hip_runtime.h>
#include <hip/hip_fp16.h>
#include <math.h>

// ---------------------------------------------------------------------------
// SuperCKAN forward:
//   conv1 (k=5, grid5, n=12)  + pool -> (256,12,12,12)
//   conv2 (k=4, grid10, n=12) + pool -> (256,144,4,4)
//   conv3 (k=3, grid10, n=24) + pool -> (256,3456)
//   fc: x @ (w2@w1)^T + (b1@w2^T + b2) -> (256,10)
//
// R7: (a) REVERT R6's global/LDS split (divergent L1 gather regressed 15us).
// (b) weight tables stored in f16: LDS bytes/element halved (the conv loop is
// LDS-bandwidth-bound). Rows 16B-aligned: NP=16 halves for N=12, NP=24 for
// N=24. Reads: 1xb128+1xb64 per row (N=12) / 3xb128 (N=24).
// Accumulation and activations stay fp32; error budget ~1e-3 << 5.2e-3.
// R4/R5 design kept: zero-padded tables [base][4 pad][G][4 pad], s clamped to
// [-1,NINT] (boundaries hit pad rows, no masking); strided prep; float4 fc.
// ---------------------------------------------------------------------------

#define B_BATCH 256

// Weight layout per layer: [K*K][R][NP] halves, R = G+9:
//   row 0: base (silu) w; rows 1..4: zero pad; rows 5..G+4: spline g=0..G-1
//   (scaler folded); rows G+5..G+8: zero pad. Cols N..NP-1: zero pad.
// Spline rows for interval t (clamped to [-1, NINT]) are t+2+m, m=0..3.

__device__ __forceinline__ void hfma_u32(unsigned v, float c, float& a0, float& a1)
{
    union { unsigned u; __half2 h; } cv; cv.u = v;
    float2 f = __half22float2(cv.h);
    a0 = fmaf(c, f.x, a0);
    a1 = fmaf(c, f.y, a1);
}

// apply one weight row (N halves) scaled by coef into acc[N]
template <int N>
__device__ __forceinline__ void row_fma(const __half* __restrict__ row, float coef,
                                        float* __restrict__ acc)
{
#pragma unroll
    for (int c = 0; c < N / 8; ++c) {
        uint4 u = *reinterpret_cast<const uint4*>(row + c * 8);
        hfma_u32(u.x, coef, acc[c * 8 + 0], acc[c * 8 + 1]);
        hfma_u32(u.y, coef, acc[c * 8 + 2], acc[c * 8 + 3]);
        hfma_u32(u.z, coef, acc[c * 8 + 4], acc[c * 8 + 5]);
        hfma_u32(u.w, coef, acc[c * 8 + 6], acc[c * 8 + 7]);
    }
    if constexpr ((N % 8) != 0) {
        constexpr int b = (N / 8) * 8;
        uint2 u = *reinterpret_cast<const uint2*>(row + b);
        hfma_u32(u.x, coef, acc[b + 0], acc[b + 1]);
        hfma_u32(u.y, coef, acc[b + 2], acc[b + 3]);
    }
}

// ---- unified prep kernel ---------------------------------------------------
// block 0: W1m   block 1: W2m   block 2: W3m   block 3: bf   blocks 4..138: Wf
__global__ __launch_bounds__(256) void prep_all(
    const float* __restrict__ bw1, const float* __restrict__ sw1, const float* __restrict__ sc1,
    const float* __restrict__ bw2, const float* __restrict__ sw2, const float* __restrict__ sc2,
    const float* __restrict__ bw3, const float* __restrict__ sw3, const float* __restrict__ sc3,
    const float* __restrict__ b1, const float* __restrict__ w2, const float* __restrict__ b2,
    const float* __restrict__ w1,
    __half* __restrict__ W1m, __half* __restrict__ W2m, __half* __restrict__ W3m,
    float* __restrict__ bf, float* __restrict__ Wf)
{
    int blk = blockIdx.x;
    int tid = threadIdx.x;
    if (blk == 0) {                      // layer1: 300 entries, R=17, NP=16, G=8
        for (int i = tid; i < 25 * 17 * 16; i += 256) W1m[i] = __float2half(0.f);
        __syncthreads();
        for (int e = tid; e < 300; e += 256) {
            int n = e / 25, k = e % 25;
            float sc = sc1[n * 25 + k];
            W1m[(k * 17 + 0) * 16 + n] = __float2half(bw1[n * 25 + k]);
            for (int g = 0; g < 8; ++g)
                W1m[(k * 17 + 5 + g) * 16 + n] = __float2half(sw1[(n * 25 + k) * 8 + g] * sc);
        }
    } else if (blk == 1) {               // layer2: 192 entries, R=22, NP=16, G=13
        for (int i = tid; i < 16 * 22 * 16; i += 256) W2m[i] = __float2half(0.f);
        __syncthreads();
        for (int e = tid; e < 192; e += 256) {
            int n = e / 16, k = e % 16;
            float sc = sc2[n * 16 + k];
            W2m[(k * 22 + 0) * 16 + n] = __float2half(bw2[n * 16 + k]);
            for (int g = 0; g < 13; ++g)
                W2m[(k * 22 + 5 + g) * 16 + n] = __float2half(sw2[(n * 16 + k) * 13 + g] * sc);
        }
    } else if (blk == 2) {               // layer3: 216 entries, R=22, NP=24, G=13
        for (int i = tid; i < 9 * 22 * 24; i += 256) W3m[i] = __float2half(0.f);
        __syncthreads();
        for (int e = tid; e < 216; e += 256) {
            int n = e / 9, k = e % 9;
            float sc = sc3[n * 9 + k];
            W3m[(k * 22 + 0) * 24 + n] = __float2half(bw3[n * 9 + k]);
            for (int g = 0; g < 13; ++g)
                W3m[(k * 22 + 5 + g) * 24 + n] = __float2half(sw3[(n * 9 + k) * 13 + g] * sc);
        }
    } else if (blk == 3) {               // folded bias (first wave only)
        if (tid < 64) {
            int lane = tid;
            for (int n = 0; n < 10; ++n) {
                float s = 0.f;
                for (int j = lane; j < 256; j += 64) s = fmaf(b1[j], w2[n * 256 + j], s);
                for (int o = 32; o; o >>= 1) s += __shfl_down(s, o, 64);
                if (lane == 0) bf[n] = s + b2[n];
            }
        }
    } else {                             // Wf = w2 @ w1 (10 x 3456)
        int gid = (blk - 4) * 256 + tid; // 135*256 = 34560 exact
        int n = gid / 3456, m = gid % 3456;
        float s = 0.f;
        for (int j = 0; j < 256; ++j)
            s = fmaf(w2[n * 256 + j], w1[j * 3456 + m], s);
        Wf[n * 3456 + m] = s;
    }
}

// ---- fused KAN conv + 2x2 maxpool, sparse spline, f16 weights -------------
// Thread quad (4 lanes, sub = 2x2 conv position) per pooled output position.
// Grid is EXACT (B_BATCH*C*POS*4 threads): no early return.
template <int K, int NINT, int G, int N, int NP, int C, int HIN, int WIN,
          int HP, int WP>
__global__ __launch_bounds__(256, 4) void kan_conv_pool(
    const float* __restrict__ in, const __half* __restrict__ W,
    float* __restrict__ out, float g0, float invh)
{
    constexpr int R = G + 9;
    constexpr int POS = HP * WP;
    constexpr int WSZ = K * K * R * NP;        // halves
    static_assert((WSZ % 8) == 0 && (N % 4) == 0, "alignment");

    __shared__ __half sw[WSZ];
    for (int i = threadIdx.x; i < WSZ / 8; i += 256)
        reinterpret_cast<uint4*>(sw)[i] = reinterpret_cast<const uint4*>(W)[i];
    __syncthreads();

    int tid = blockIdx.x * 256 + threadIdx.x;

    int sub = tid & 3;
    int rem = tid >> 2;
    int pos = rem % POS;
    int bc  = rem / POS;               // b*C + c
    int pi = pos / WP, pj = pos % WP;
    int p = 2 * pi + (sub >> 1);
    int q = 2 * pj + (sub & 1);

    const float* inp = in + bc * (HIN * WIN);

    float acc[N];
#pragma unroll
    for (int n = 0; n < N; ++n) acc[n] = 0.f;

#pragma unroll 1
    for (int dy = 0; dy < K; ++dy) {
#pragma unroll
        for (int dx = 0; dx < K; ++dx) {
            float v = inp[(p + dy) * WIN + (q + dx)];

            float s  = (v - g0) * invh;
            float sc = fminf(fmaxf(s, -1.0f), (float)NINT);  // sentinels hit pads
            float sf = floorf(sc);
            int   t  = (int)sf;
            float u  = sc - sf;                 // in [0,1]: coeffs stay finite
            float u2 = u * u, u3 = u2 * u;
            float um = 1.0f - u;
            float c0 = um * um * um * (1.0f / 6.0f);
            float c1 = (3.0f * u3 - 6.0f * u2 + 4.0f) * (1.0f / 6.0f);
            float c2 = (-3.0f * u3 + 3.0f * u2 + 3.0f * u + 1.0f) * (1.0f / 6.0f);
            float c3 = u3 * (1.0f / 6.0f);
            float sv = v / (1.0f + __expf(-v)); // silu

            const __half* wk = sw + (dy * K + dx) * (R * NP); // base row
            const __half* wt = wk + (t + 2) * NP;             // spline rows

            row_fma<N>(wk,          sv, acc);
            row_fma<N>(wt + 0 * NP, c0, acc);
            row_fma<N>(wt + 1 * NP, c1, acc);
            row_fma<N>(wt + 2 * NP, c2, acc);
            row_fma<N>(wt + 3 * NP, c3, acc);
        }
    }

    // 2x2 maxpool across the lane quad
#pragma unroll
    for (int n = 0; n < N; ++n) {
        acc[n] = fmaxf(acc[n], __shfl_xor(acc[n], 1, 64));
        acc[n] = fmaxf(acc[n], __shfl_xor(acc[n], 2, 64));
    }

    // each of the 4 lanes writes N/4 channels
    constexpr int NPL = N / 4;
    int n0 = sub * NPL;
    float* op = out + bc * (N * POS) + pos;
#pragma unroll
    for (int i = 0; i < NPL; ++i)
        op[(n0 + i) * POS] = acc[n0 + i];
}

// ---- final GEMV: out = x3 @ Wf^T + bf; grid 2560 waves exact --------------
__global__ __launch_bounds__(256) void fc_kernel(
    const float* __restrict__ x3, const float* __restrict__ Wf,
    const float* __restrict__ bf, float* __restrict__ out)
{
    int wid  = (blockIdx.x * 256 + threadIdx.x) >> 6;
    int lane = threadIdx.x & 63;
    int b = wid / 10, n = wid - b * 10;
    const float4* xr = (const float4*)(x3 + b * 3456);
    const float4* wr = (const float4*)(Wf + n * 3456);
    float s = 0.f;
#pragma unroll
    for (int i = 0; i < 13; ++i) {       // 13*64*4 = 3328 floats
        float4 a = xr[lane + i * 64];
        float4 w = wr[lane + i * 64];
        s = fmaf(a.x, w.x, s); s = fmaf(a.y, w.y, s);
        s = fmaf(a.z, w.z, s); s = fmaf(a.w, w.w, s);
    }
    const float* xs = x3 + b * 3456 + 3328;   // remainder 128 floats
    const float* wsp = Wf + n * 3456 + 3328;
    s = fmaf(xs[lane], wsp[lane], s);
    s = fmaf(xs[lane + 64], wsp[lane + 64], s);
    for (int o = 32; o; o >>= 1) s += __shfl_down(s, o, 64);
    if (lane == 0) out[wid] = s + bf[n];
}

// ---------------------------------------------------------------------------
extern "C" void kernel_launch(void* const* d_in, const int* in_sizes, int n_in,
                              void* d_out, int out_size, void* d_ws, size_t ws_size,
                              hipStream_t stream)
{
    (void)in_sizes; (void)n_in; (void)out_size; (void)ws_size;
    const float* x   = (const float*)d_in[0];
    const float* bw1 = (const float*)d_in[1];
    const float* sw1 = (const float*)d_in[2];
    const float* sc1 = (const float*)d_in[3];
    const float* bw2 = (const float*)d_in[4];
    const float* sw2 = (const float*)d_in[5];
    const float* sc2 = (const float*)d_in[6];
    const float* bw3 = (const float*)d_in[7];
    const float* sw3 = (const float*)d_in[8];
    const float* sc3 = (const float*)d_in[9];
    const float* w1  = (const float*)d_in[10];
    const float* b1  = (const float*)d_in[11];
    const float* w2  = (const float*)d_in[12];
    const float* b2  = (const float*)d_in[13];

    float* ws  = (float*)d_ws;
    // f16 tables (sizes in halves -> /2 floats): W1m 6800h=3400f,
    // W2m 5632h=2816f, W3m 4752h=2376f
    __half* W1m = (__half*)(ws);           // floats [0, 3400)
    __half* W2m = (__half*)(ws + 3400);    // floats [3400, 6216)
    __half* W3m = (__half*)(ws + 6216);    // floats [6216, 8592)
    float*  bf  = ws + 8592;               // 10 (+pad)
    float*  Wf  = ws + 8640;               // 34560
    float*  o1  = ws + 43200;              // 256*12*12*12 = 442368
    float*  o2  = ws + 485568;             // 256*144*4*4  = 589824
    float*  x3  = ws + 1075392;            // 256*3456     = 884736
    float*  out = (float*)d_out;

    prep_all<<<139, 256, 0, stream>>>(bw1, sw1, sc1, bw2, sw2, sc2,
                                      bw3, sw3, sc3, b1, w2, b2, w1,
                                      W1m, W2m, W3m, bf, Wf);

    const float h1 = 2.0f / 5.0f, h2 = 2.0f / 10.0f;
    // layer1: K=5, NINT=11, G=8,  N=12, NP=16, C=1,   28x28 -> pooled 12x12
    kan_conv_pool<5, 11, 8, 12, 16, 1, 28, 28, 12, 12>
        <<<576, 256, 0, stream>>>(x, W1m, o1, -3.0f * h1 - 1.0f, 1.0f / h1);
    // layer2: K=4, NINT=16, G=13, N=12, NP=16, C=12,  12x12 -> pooled 4x4
    kan_conv_pool<4, 16, 13, 12, 16, 12, 12, 12, 4, 4>
        <<<768, 256, 0, stream>>>(o1, W2m, o2, -3.0f * h2 - 1.0f, 1.0f / h2);
    // layer3: K=3, NINT=16, G=13, N=24, NP=24, C=144, 4x4  -> pooled 1x1
    kan_conv_pool<3, 16, 13, 24, 24, 144, 4, 4, 1, 1>
        <<<576, 256, 0, stream>>>(o2, W3m, x3, -3.0f * h2 - 1.0f, 1.0f / h2);

    fc_kernel<<<640, 256, 0, stream>>>(x3, Wf, bf, out);
}

// Round 9
// 77.840 us; speedup vs baseline: 1.3849x; 1.3849x over previous
//
#include <hip/hip_runtime.h>
#include <math.h>

// ---------------------------------------------------------------------------
// SuperCKAN forward:
//   conv1 (k=5, grid5, n=12)  + pool -> (256,12,12,12)
//   conv2 (k=4, grid10, n=12) + pool -> (256,144,4,4)
//   conv3 (k=3, grid10, n=24) + pool -> (256,3456)
//   fc: x @ (w2@w1)^T + (b1@w2^T + b2) -> (256,10)
// All fp32.
//
// R8: REVERT R7's f16 tables (row_fma took acc as float* -> alloca survived ->
// scratch storm: FETCH 38MB/WRITE 108MB per conv, 49us). Back to R5's proven
// fp32 inner loop. NEW: 2-way dy-split threading -- each conv window is
// computed by TWO threads (lane bit2 = half), combined with one shfl_xor(4)
// before the pool reduce. Work unchanged, waves doubled (conv occupancy
// ~30% -> ~60%) to keep the LDS pipe fed through the VALU feature phase.
// R4/R5 design kept: zero-padded tables [base][4 pad][G][4 pad], s clamped to
// [-1,NINT] (boundaries hit pad rows, no masking); strided prep; float4 fc.
// ---------------------------------------------------------------------------

#define B_BATCH 256

// Weight layout per layer: [K*K][R][N], R = G+9:
//   row 0: base (silu) w; rows 1..4: zero pad; rows 5..G+4: spline g=0..G-1
//   (scaler folded); rows G+5..G+8: zero pad.
// Spline rows for interval t (clamped to [-1, NINT]) are t+2+m, m=0..3.

// ---- unified prep kernel ---------------------------------------------------
// block 0: W1m   block 1: W2m   block 2: W3m   block 3: bf   blocks 4..138: Wf
__global__ __launch_bounds__(256) void prep_all(
    const float* __restrict__ bw1, const float* __restrict__ sw1, const float* __restrict__ sc1,
    const float* __restrict__ bw2, const float* __restrict__ sw2, const float* __restrict__ sc2,
    const float* __restrict__ bw3, const float* __restrict__ sw3, const float* __restrict__ sc3,
    const float* __restrict__ b1, const float* __restrict__ w2, const float* __restrict__ b2,
    const float* __restrict__ w1,
    float* __restrict__ W1m, float* __restrict__ W2m, float* __restrict__ W3m,
    float* __restrict__ bf, float* __restrict__ Wf)
{
    int blk = blockIdx.x;
    int tid = threadIdx.x;
    if (blk == 0) {                      // layer1: 300 entries, R=17, N=12, G=8
        for (int i = tid; i < 25 * 17 * 12; i += 256) W1m[i] = 0.f;
        __syncthreads();
        for (int e = tid; e < 300; e += 256) {
            int n = e / 25, k = e % 25;
            float sc = sc1[n * 25 + k];
            W1m[(k * 17 + 0) * 12 + n] = bw1[n * 25 + k];
            for (int g = 0; g < 8; ++g)
                W1m[(k * 17 + 5 + g) * 12 + n] = sw1[(n * 25 + k) * 8 + g] * sc;
        }
    } else if (blk == 1) {               // layer2: 192 entries, R=22, N=12, G=13
        for (int i = tid; i < 16 * 22 * 12; i += 256) W2m[i] = 0.f;
        __syncthreads();
        for (int e = tid; e < 192; e += 256) {
            int n = e / 16, k = e % 16;
            float sc = sc2[n * 16 + k];
            W2m[(k * 22 + 0) * 12 + n] = bw2[n * 16 + k];
            for (int g = 0; g < 13; ++g)
                W2m[(k * 22 + 5 + g) * 12 + n] = sw2[(n * 16 + k) * 13 + g] * sc;
        }
    } else if (blk == 2) {               // layer3: 216 entries, R=22, N=24, G=13
        for (int i = tid; i < 9 * 22 * 24; i += 256) W3m[i] = 0.f;
        __syncthreads();
        for (int e = tid; e < 216; e += 256) {
            int n = e / 9, k = e % 9;
            float sc = sc3[n * 9 + k];
            W3m[(k * 22 + 0) * 24 + n] = bw3[n * 9 + k];
            for (int g = 0; g < 13; ++g)
                W3m[(k * 22 + 5 + g) * 24 + n] = sw3[(n * 9 + k) * 13 + g] * sc;
        }
    } else if (blk == 3) {               // folded bias (first wave only)
        if (tid < 64) {
            int lane = tid;
            for (int n = 0; n < 10; ++n) {
                float s = 0.f;
                for (int j = lane; j < 256; j += 64) s = fmaf(b1[j], w2[n * 256 + j], s);
                for (int o = 32; o; o >>= 1) s += __shfl_down(s, o, 64);
                if (lane == 0) bf[n] = s + b2[n];
            }
        }
    } else {                             // Wf = w2 @ w1 (10 x 3456)
        int gid = (blk - 4) * 256 + tid; // 135*256 = 34560 exact
        int n = gid / 3456, m = gid % 3456;
        float s = 0.f;
        for (int j = 0; j < 256; ++j)
            s = fmaf(w2[n * 256 + j], w1[j * 3456 + m], s);
        Wf[n * 3456 + m] = s;
    }
}

// ---- fused KAN conv + 2x2 maxpool, sparse spline, dy-split ----------------
// 8 lanes per pooled output: bits 0-1 = conv position in the 2x2 pool quad,
// bit 2 = dy work-half. Grid is EXACT (B_BATCH*C*POS*8 threads): no early
// return, weight reads stay in uniform control flow.
template <int K, int NINT, int G, int N, int C, int HIN, int WIN, int HP, int WP>
__global__ __launch_bounds__(256, 4) void kan_conv_pool(
    const float* __restrict__ in, const float* __restrict__ W,
    float* __restrict__ out, float g0, float invh)
{
    constexpr int R = G + 9;
    constexpr int POS = HP * WP;
    constexpr int WSZ = K * K * R * N;
    constexpr int DYS = (K + 1) / 2;          // dy split point
    static_assert((N % 4) == 0, "alignment");

    __shared__ float sw[WSZ];
    for (int i = threadIdx.x; i < WSZ; i += 256) sw[i] = W[i];
    __syncthreads();

    int tid = blockIdx.x * 256 + threadIdx.x;

    int sub = tid & 3;                 // conv position within pool quad
    int h   = (tid >> 2) & 1;          // dy half
    int rem = tid >> 3;
    int pos = rem % POS;
    int bc  = rem / POS;               // b*C + c
    int pi = pos / WP, pj = pos % WP;
    int p = 2 * pi + (sub >> 1);
    int q = 2 * pj + (sub & 1);

    const float* inp = in + bc * (HIN * WIN);

    int dy0 = h ? DYS : 0;
    int dy1 = h ? K   : DYS;

    float acc[N];
#pragma unroll
    for (int n = 0; n < N; ++n) acc[n] = 0.f;

#pragma unroll 1
    for (int dy = dy0; dy < dy1; ++dy) {
#pragma unroll
        for (int dx = 0; dx < K; ++dx) {
            float v = inp[(p + dy) * WIN + (q + dx)];

            float s  = (v - g0) * invh;
            float sc = fminf(fmaxf(s, -1.0f), (float)NINT);  // sentinels hit pads
            float sf = floorf(sc);
            int   t  = (int)sf;
            float u  = sc - sf;                 // in [0,1]: coeffs stay finite
            float u2 = u * u, u3 = u2 * u;
            float um = 1.0f - u;
            float c0 = um * um * um * (1.0f / 6.0f);
            float c1 = (3.0f * u3 - 6.0f * u2 + 4.0f) * (1.0f / 6.0f);
            float c2 = (-3.0f * u3 + 3.0f * u2 + 3.0f * u + 1.0f) * (1.0f / 6.0f);
            float c3 = u3 * (1.0f / 6.0f);
            float sv = v / (1.0f + __expf(-v)); // silu

            const float* wk = sw + (dy * K + dx) * (R * N);  // base row (uniform)
            const float* wt = wk + (t + 2) * N;              // spline row block

#pragma unroll
            for (int n4 = 0; n4 < N / 4; ++n4) {
                float4 wb = ((const float4*)wk)[n4];
                float4 w0 = ((const float4*)(wt + 0 * N))[n4];
                float4 w1_ = ((const float4*)(wt + 1 * N))[n4];
                float4 w2_ = ((const float4*)(wt + 2 * N))[n4];
                float4 w3_ = ((const float4*)(wt + 3 * N))[n4];
                float a0 = acc[n4 * 4 + 0], a1 = acc[n4 * 4 + 1];
                float a2 = acc[n4 * 4 + 2], a3 = acc[n4 * 4 + 3];
                a0 = fmaf(sv, wb.x, a0); a1 = fmaf(sv, wb.y, a1);
                a2 = fmaf(sv, wb.z, a2); a3 = fmaf(sv, wb.w, a3);
                a0 = fmaf(c0, w0.x, a0); a1 = fmaf(c0, w0.y, a1);
                a2 = fmaf(c0, w0.z, a2); a3 = fmaf(c0, w0.w, a3);
                a0 = fmaf(c1, w1_.x, a0); a1 = fmaf(c1, w1_.y, a1);
                a2 = fmaf(c1, w1_.z, a2); a3 = fmaf(c1, w1_.w, a3);
                a0 = fmaf(c2, w2_.x, a0); a1 = fmaf(c2, w2_.y, a1);
                a2 = fmaf(c2, w2_.z, a2); a3 = fmaf(c2, w2_.w, a3);
                a0 = fmaf(c3, w3_.x, a0); a1 = fmaf(c3, w3_.y, a1);
                a2 = fmaf(c3, w3_.z, a2); a3 = fmaf(c3, w3_.w, a3);
                acc[n4 * 4 + 0] = a0; acc[n4 * 4 + 1] = a1;
                acc[n4 * 4 + 2] = a2; acc[n4 * 4 + 3] = a3;
            }
        }
    }

    // combine dy halves, then 2x2 maxpool across the lane quad
#pragma unroll
    for (int n = 0; n < N; ++n) {
        float a = acc[n];
        a += __shfl_xor(a, 4, 64);                 // dy-half combine
        a = fmaxf(a, __shfl_xor(a, 1, 64));        // pool
        a = fmaxf(a, __shfl_xor(a, 2, 64));
        acc[n] = a;
    }

    // h==0 quad writes N/4 channels per lane
    constexpr int NPL = N / 4;
    if (h == 0) {
        int n0 = sub * NPL;
        float* op = out + bc * (N * POS) + pos;
#pragma unroll
        for (int i = 0; i < NPL; ++i)
            op[(n0 + i) * POS] = acc[n0 + i];
    }
}

// ---- final GEMV: out = x3 @ Wf^T + bf; grid 2560 waves exact --------------
__global__ __launch_bounds__(256) void fc_kernel(
    const float* __restrict__ x3, const float* __restrict__ Wf,
    const float* __restrict__ bf, float* __restrict__ out)
{
    int wid  = (blockIdx.x * 256 + threadIdx.x) >> 6;
    int lane = threadIdx.x & 63;
    int b = wid / 10, n = wid - b * 10;
    const float4* xr = (const float4*)(x3 + b * 3456);
    const float4* wr = (const float4*)(Wf + n * 3456);
    float s = 0.f;
#pragma unroll
    for (int i = 0; i < 13; ++i) {       // 13*64*4 = 3328 floats
        float4 a = xr[lane + i * 64];
        float4 w = wr[lane + i * 64];
        s = fmaf(a.x, w.x, s); s = fmaf(a.y, w.y, s);
        s = fmaf(a.z, w.z, s); s = fmaf(a.w, w.w, s);
    }
    const float* xs = x3 + b * 3456 + 3328;   // remainder 128 floats
    const float* wsp = Wf + n * 3456 + 3328;
    s = fmaf(xs[lane], wsp[lane], s);
    s = fmaf(xs[lane + 64], wsp[lane + 64], s);
    for (int o = 32; o; o >>= 1) s += __shfl_down(s, o, 64);
    if (lane == 0) out[wid] = s + bf[n];
}

// ---------------------------------------------------------------------------
extern "C" void kernel_launch(void* const* d_in, const int* in_sizes, int n_in,
                              void* d_out, int out_size, void* d_ws, size_t ws_size,
                              hipStream_t stream)
{
    (void)in_sizes; (void)n_in; (void)out_size; (void)ws_size;
    const float* x   = (const float*)d_in[0];
    const float* bw1 = (const float*)d_in[1];
    const float* sw1 = (const float*)d_in[2];
    const float* sc1 = (const float*)d_in[3];
    const float* bw2 = (const float*)d_in[4];
    const float* sw2 = (const float*)d_in[5];
    const float* sc2 = (const float*)d_in[6];
    const float* bw3 = (const float*)d_in[7];
    const float* sw3 = (const float*)d_in[8];
    const float* sc3 = (const float*)d_in[9];
    const float* w1  = (const float*)d_in[10];
    const float* b1  = (const float*)d_in[11];
    const float* w2  = (const float*)d_in[12];
    const float* b2  = (const float*)d_in[13];

    float* ws  = (float*)d_ws;
    float* W1m = ws;              // 25*17*12 = 5100
    float* W2m = ws + 5100;       // 16*22*12 = 4224
    float* W3m = ws + 9324;       // 9*22*24  = 4752
    float* bf  = ws + 14080;      // 10 (+pad, 16B aligned)
    float* Wf  = ws + 14144;      // 34560
    float* o1  = ws + 48704;      // 256*12*12*12 = 442368
    float* o2  = ws + 491072;     // 256*144*4*4  = 589824
    float* x3  = ws + 1080896;    // 256*3456     = 884736
    float* out = (float*)d_out;

    prep_all<<<139, 256, 0, stream>>>(bw1, sw1, sc1, bw2, sw2, sc2,
                                      bw3, sw3, sc3, b1, w2, b2, w1,
                                      W1m, W2m, W3m, bf, Wf);

    const float h1 = 2.0f / 5.0f, h2 = 2.0f / 10.0f;
    // layer1: K=5, NINT=11, G=8,  N=12, C=1,   28x28 -> pooled 12x12 (8 ln/out)
    kan_conv_pool<5, 11, 8, 12, 1, 28, 28, 12, 12>
        <<<1152, 256, 0, stream>>>(x, W1m, o1, -3.0f * h1 - 1.0f, 1.0f / h1);
    // layer2: K=4, NINT=16, G=13, N=12, C=12,  12x12 -> pooled 4x4
    kan_conv_pool<4, 16, 13, 12, 12, 12, 12, 4, 4>
        <<<1536, 256, 0, stream>>>(o1, W2m, o2, -3.0f * h2 - 1.0f, 1.0f / h2);
    // layer3: K=3, NINT=16, G=13, N=24, C=144, 4x4  -> pooled 1x1
    kan_conv_pool<3, 16, 13, 24, 144, 4, 4, 1, 1>
        <<<1152, 256, 0, stream>>>(o2, W3m, x3, -3.0f * h2 - 1.0f, 1.0f / h2);

    fc_kernel<<<640, 256, 0, stream>>>(x3, Wf, bf, out);
}